// Round 7
// baseline (5451.498 us; speedup 1.0000x reference)
//
#include <hip/hip_runtime.h>
#include <hip/hip_bf16.h>

#define T_SEQ 512
#define BATCH 256
#define HID   1024
#define EMBD  256
#define NCLS  10

typedef __bf16 bf16x8 __attribute__((ext_vector_type(8)));
typedef float  floatx16 __attribute__((ext_vector_type(16)));
typedef float  floatx2 __attribute__((ext_vector_type(2)));
typedef unsigned short ushortx8 __attribute__((ext_vector_type(8)));

__device__ __forceinline__ unsigned int f2bf(float f) {
    unsigned int u = __builtin_bit_cast(unsigned int, f);
    u += 0x7fffu + ((u >> 16) & 1u);
    return u >> 16;
}
__device__ __forceinline__ float sig_fast(float x) {
    return __builtin_amdgcn_rcpf(1.0f + __expf(-x));
}
__device__ __forceinline__ float tanh_fast(float x) {
    return 1.0f - 2.0f * __builtin_amdgcn_rcpf(1.0f + __expf(2.0f * x));
}

// -------------------- prep: XW[tok][gate][n] = emb[tok] @ Wx_gate + b_gate ---
__global__ void prep_xw_kernel(const float* __restrict__ emb,
                               const float* __restrict__ wgx, const float* __restrict__ wix,
                               const float* __restrict__ wfx, const float* __restrict__ wox,
                               const float* __restrict__ bg,  const float* __restrict__ bi,
                               const float* __restrict__ bf,  const float* __restrict__ bo,
                               float* __restrict__ XW) {
    int gid = blockIdx.x * blockDim.x + threadIdx.x;     // 3*4*1024 = 12288
    if (gid >= 3 * 4 * HID) return;
    int tok  = gid >> 12;
    int gate = (gid >> 10) & 3;
    int n    = gid & 1023;
    const float* W = gate == 0 ? wgx : gate == 1 ? wix : gate == 2 ? wfx : wox;
    const float* B = gate == 0 ? bg  : gate == 1 ? bi  : gate == 2 ? bf  : bo;
    float acc = B[n];
    const float* e = emb + tok * EMBD;
    for (int k = 0; k < EMBD; ++k) acc += e[k] * W[k * HID + n];
    XW[gid] = acc;
}

// ---- prep: Wt in 32x32x16 MFMA B-fragment order, (gate-pair, k-quarter) waves.
// Wave (w, gp, kq) handles gates {2gp, 2gp+1} over ksteps kk = kq*16 + i.
// frag = (((w*2+gp)*4+kq)*16 + i)*2 + gsub ; Wt[frag*512 + lane*8 + e]
//   = bf16( W_{2gp+gsub}[k = kk*16 + (lane>>5)*8 + e][j = w*32 + (lane&31)] )
__global__ void prep_w_kernel(const float* __restrict__ wgh, const float* __restrict__ wih,
                              const float* __restrict__ wfh, const float* __restrict__ woh,
                              unsigned short* __restrict__ Wt) {
    int bid  = blockIdx.x;                // 8192 = w(32) x gp(2) x kq(4) x i(16) x gsub(2)
    int gsub = bid & 1;
    int i    = (bid >> 1) & 15;
    int kq   = (bid >> 5) & 3;
    int gp   = (bid >> 7) & 1;
    int w    = bid >> 8;
    int g    = gp * 2 + gsub;
    const float* W = g == 0 ? wgh : g == 1 ? wih : g == 2 ? wfh : woh;
    int lane = threadIdx.x;               // 64
    int j    = w * 32 + (lane & 31);
    int kk   = kq * 16 + i;
    int k0   = kk * 16 + (lane >> 5) * 8;
    ushortx8 o8;
    #pragma unroll
    for (int e = 0; e < 8; ++e) o8[e] = (unsigned short)f2bf(W[(k0 + e) * HID + j]);
    int frag = (((w * 2 + gp) * 4 + kq) * 16 + i) * 2 + gsub;
    *(ushortx8*)&Wt[frag * 512 + lane * 8] = o8;
}

// -------------------- persistent recurrent kernel ---------------------------
// 256 WGs x 512 threads. grp = blockIdx%8 owns 32 batch rows; w = blockIdx/8
// owns 32 hidden cols. Wave wv: gate-pair gp = wv>>2, k-quarter kq = wv&3.
//
// R13: the step is LDS-instruction-throughput-bound (resource model from
// R9/R12 evidence: GEMM A-reads 256xb128=3072cyc + staging 770 + scatter 740
// + ew 620 = 5200 of 8330 cyc/step). Fix: delete the A-path from LDS.
//  - h(s) A-fragments load DIRECTLY from L2 into registers: per lane 16
//    fragments (16B contiguous row-slices), as 32 independent 8B agent-scope
//    (sc0) loads — the exact load type R0's staging used (no buffer_inv, no
//    coherence traps), bulk-issued into static av[16] so the compiler emits
//    counted vmcnts (no R8 latency chaining).
//  - no hs LDS buffer, no staging writes, no GEMM ds_reads. LDS/step drops
//    ~5200 -> ~2750 cyc (scatter + 16-tile ew reduction, R9's proven math).
//  - L2 read/WG/step: 64->128 KB (gp pairs read the same quarter); XCD-
//    shared ~2200 cyc, overlapped with MFMA across 8 skewed waves.
// Sync protocol, 3 barriers/step, publish: R0 verbatim (R10/R11 lessons:
// no agent/system fences in-loop, no global RMWs, single-writer plain-store
// flags, wave0-only spin). Parity-2 safety: loads happen before publish,
// same as R0's stage phase.
__global__ __launch_bounds__(512, 2)
void lstm_kernel(const int* __restrict__ x, const float* __restrict__ XW,
                 const unsigned short* __restrict__ Wt,
                 unsigned int* __restrict__ hbuf32, int* __restrict__ flags,
                 int* __restrict__ xflag) {
    __shared__ float gbuf[16 * 32 * 36];          // [gate][kq][row][col+pad] (73728 B)
    __shared__ float xwl[384];                    // [tok][gate][32 cols]     (1536 B)
    __shared__ unsigned char xtok[32 * 512];      // tokens, byte-packed      (16384 B)
    __shared__ int use_local_sh;

    const int tid  = threadIdx.x;
    const int grp  = blockIdx.x & 7;
    const int w    = blockIdx.x >> 3;
    const int wv   = tid >> 6;
    const int gp   = wv >> 2;                  // gate pair: gates {2gp, 2gp+1}
    const int kq   = wv & 3;                   // k-quarter: kk in [kq*16, kq*16+16)
    const int lane = tid & 63;
    const int m32  = lane & 31;
    const int hv5  = lane >> 5;

    // ---- XCD-locality check (one-time, system-scope => placement-safe) ----
    {
        int xcc = 0;
        asm volatile("s_getreg_b32 %0, hwreg(HW_REG_XCC_ID)" : "=s"(xcc));
        if (tid == 0) {
            __hip_atomic_store(&xflag[grp * 32 + w], xcc + 1, __ATOMIC_RELAXED,
                               __HIP_MEMORY_SCOPE_SYSTEM);
        }
        if (wv == 0) {
            int v;
            for (;;) {
                v = __hip_atomic_load(&xflag[grp * 32 + (lane & 31)], __ATOMIC_RELAXED,
                                      __HIP_MEMORY_SCOPE_SYSTEM);
                if (__all(v != 0)) break;
                __builtin_amdgcn_s_sleep(2);
            }
            int v0 = __shfl(v, 0, 64);
            if (lane == 0) use_local_sh = __all(v == v0) ? 1 : 0;
        }
    }

    // one-time: B fragments into registers (128 regs/lane, AGPR-backed)
    // Bf[i*2+gsub] = B-frag for kstep kq*16+i, gate 2gp+gsub.
    bf16x8 Bf[32];
    {
        const unsigned short* wb = Wt + (size_t)(((w * 2 + gp) * 4 + kq) * 32) * 512
                                      + (size_t)lane * 8;
        #pragma unroll
        for (int t = 0; t < 32; ++t)
            Bf[t] = *(const bf16x8*)(wb + t * 512);
    }
    // one-time: XW slice into LDS
    if (tid < 384) {
        int tok = tid >> 7, g = (tid >> 5) & 3, jl = tid & 31;
        xwl[tid] = XW[(tok * 4 + g) * HID + w * 32 + jl];
    }
    // one-time: token table into LDS (byte-packed)
    #pragma unroll
    for (int it = 0; it < 32; ++it) {
        int flat = it * 512 + tid;                 // 16384 tokens
        int row  = flat >> 9;
        int col  = flat & 511;
        xtok[flat] = (unsigned char)x[(grp * 32 + row) * T_SEQ + col];
    }
    __syncthreads();
    const bool use_local = (use_local_sh != 0);

    // elementwise ownership: thread -> row = tid>>4, cols jc2*2..+2
    const int erow = tid >> 4;
    const int jc2  = tid & 15;
    float cst[2] = {0.f, 0.f};

    // per-lane A-load base (qwords): row (grp*32+m32), quarter kq, half hv5
    const int rowq = (grp * 32 + m32) * 256 + kq * 64 + hv5 * 2;

    for (int s = 0; s < T_SEQ; ++s) {
        // ---- wait for h(s) from all 32 group members (R0 protocol) ----
        if (s > 0) {
            if (wv == 0) {
                const int fidx = grp * 32 + (lane & 31);
                if (use_local) {
                    while (__hip_atomic_load(&flags[fidx], __ATOMIC_RELAXED,
                                             __HIP_MEMORY_SCOPE_AGENT) < s)
                        __builtin_amdgcn_s_sleep(1);
                } else {
                    while (__hip_atomic_load(&flags[fidx], __ATOMIC_RELAXED,
                                             __HIP_MEMORY_SCOPE_SYSTEM) < s)
                        __builtin_amdgcn_s_sleep(1);
                }
            }
            __syncthreads();
        }

        // ---- A-fragments: straight L2 -> registers (no LDS round trip) ----
        // kstep kk=kq*16+i: lane (m32,hv5) needs h[row][kk*16+hv5*8 ..+8]
        // = qwords rowq + i*4 (+1). 32 independent 8B sc0 loads, bulk-issued.
        const unsigned long long* hq = (const unsigned long long*)
            (hbuf32 + (size_t)(s & 1) * (BATCH * HID / 2));
        union { unsigned long long q[2]; bf16x8 a; } av[16];
        if (use_local) {
            #pragma unroll
            for (int i = 0; i < 16; ++i) {
                av[i].q[0] = __hip_atomic_load(&hq[rowq + i * 4],
                                               __ATOMIC_RELAXED, __HIP_MEMORY_SCOPE_AGENT);
                av[i].q[1] = __hip_atomic_load(&hq[rowq + i * 4 + 1],
                                               __ATOMIC_RELAXED, __HIP_MEMORY_SCOPE_AGENT);
            }
        } else {
            #pragma unroll
            for (int i = 0; i < 16; ++i) {
                av[i].q[0] = __hip_atomic_load(&hq[rowq + i * 4],
                                               __ATOMIC_RELAXED, __HIP_MEMORY_SCOPE_SYSTEM);
                av[i].q[1] = __hip_atomic_load(&hq[rowq + i * 4 + 1],
                                               __ATOMIC_RELAXED, __HIP_MEMORY_SCOPE_SYSTEM);
            }
        }

        // ---- GEMM: 2 gates x 16 ksteps, all operands in registers ----
        floatx16 acc0 = {0.f,0.f,0.f,0.f,0.f,0.f,0.f,0.f,0.f,0.f,0.f,0.f,0.f,0.f,0.f,0.f};
        floatx16 acc1 = {0.f,0.f,0.f,0.f,0.f,0.f,0.f,0.f,0.f,0.f,0.f,0.f,0.f,0.f,0.f,0.f};
        #pragma unroll
        for (int i = 0; i < 16; ++i) {
            acc0 = __builtin_amdgcn_mfma_f32_32x32x16_bf16(av[i].a, Bf[2 * i],     acc0, 0, 0, 0);
            acc1 = __builtin_amdgcn_mfma_f32_32x32x16_bf16(av[i].a, Bf[2 * i + 1], acc1, 0, 0, 0);
        }

        // ---- scatter partials (col=lane&31, row=(reg&3)+8*(reg>>2)+4*hv5) ----
        {
            float* gb0 = &gbuf[(size_t)((gp * 2 + 0) * 4 + kq) * 1152];
            float* gb1 = &gbuf[(size_t)((gp * 2 + 1) * 4 + kq) * 1152];
            #pragma unroll
            for (int reg = 0; reg < 16; ++reg) {
                int row = (reg & 3) + 8 * (reg >> 2) + 4 * hv5;
                gb0[row * 36 + m32] = acc0[reg];
                gb1[row * 36 + m32] = acc1[reg];
            }
        }
        __syncthreads();

        // ---- elementwise LSTM cell update, h(s+1) out ----
        {
            int tk = xtok[erow * 512 + s];
            const float* xb = &xwl[tk * 128];
            const int go = erow * 36 + jc2 * 2;
            #define GSUM(g) ( *(const floatx2*)&gbuf[((g) * 4 + 0) * 1152 + go] \
                            + *(const floatx2*)&gbuf[((g) * 4 + 1) * 1152 + go] \
                            + *(const floatx2*)&gbuf[((g) * 4 + 2) * 1152 + go] \
                            + *(const floatx2*)&gbuf[((g) * 4 + 3) * 1152 + go] )
            floatx2 ag = GSUM(0);
            floatx2 ai = GSUM(1);
            floatx2 af = GSUM(2);
            floatx2 ao = GSUM(3);
            #undef GSUM
            floatx2 xg = *(const floatx2*)&xb[0 * 32 + jc2 * 2];
            floatx2 xi = *(const floatx2*)&xb[1 * 32 + jc2 * 2];
            floatx2 xf = *(const floatx2*)&xb[2 * 32 + jc2 * 2];
            floatx2 xo = *(const floatx2*)&xb[3 * 32 + jc2 * 2];
            unsigned int hvv[2];
            #pragma unroll
            for (int u = 0; u < 2; ++u) {
                float g  = tanh_fast(ag[u] + xg[u]);
                float ii = sig_fast(ai[u] + xi[u]);
                float ff = sig_fast(af[u] + xf[u]);
                float oo = sig_fast(ao[u] + xo[u]);
                float cn = g * ii + cst[u] * ff;
                float h  = tanh_fast(cn) * oo;
                cst[u]   = (tk != 0) ? cn : 0.0f;   // pad = ((x+1)//2) in {0,1,1}
                hvv[u]   = f2bf(h);
            }
            unsigned int* hnext = hbuf32 + (size_t)((s + 1) & 1) * (BATCH * HID / 2);
            unsigned int* hp = &hnext[((grp * 32 + erow) * HID + w * 32 + jc2 * 2) >> 1];
            unsigned int hval = hvv[0] | (hvv[1] << 16);
            if (use_local) {
                // plain write-back store into the shared XCD L2 (no LLC RTT)
                __hip_atomic_store(hp, hval, __ATOMIC_RELAXED, __HIP_MEMORY_SCOPE_WORKGROUP);
            } else {
                __hip_atomic_store(hp, hval, __ATOMIC_RELAXED, __HIP_MEMORY_SCOPE_SYSTEM);
            }
        }
        // syncthreads drains each wave's vmcnt before s_barrier => on exit, all
        // h stores of this WG are complete at their coherence point (L2 local /
        // LLC fallback) before the flag is published.
        __syncthreads();

        if (s < T_SEQ - 1 && tid == 0) {
            if (use_local) {
                __hip_atomic_store(&flags[grp * 32 + w], s + 1,
                                   __ATOMIC_RELAXED, __HIP_MEMORY_SCOPE_WORKGROUP);
            } else {
                __hip_atomic_store(&flags[grp * 32 + w], s + 1,
                                   __ATOMIC_RELAXED, __HIP_MEMORY_SCOPE_SYSTEM);
            }
        }
    }
}

// -------------------- projection + log_softmax over batch dim ---------------
__global__ void proj_kernel(const unsigned short* __restrict__ h,
                            const float* __restrict__ wph, const float* __restrict__ bp,
                            float* __restrict__ out) {
    __shared__ float wl[HID * NCLS];
    __shared__ float red[256];
    int tid = threadIdx.x;      // = batch row
    for (int i = tid; i < HID * NCLS; i += 256) wl[i] = wph[i];
    __syncthreads();
    float p[NCLS];
    #pragma unroll
    for (int c2 = 0; c2 < NCLS; ++c2) p[c2] = bp[c2];
    const unsigned short* hr = h + tid * HID;
    for (int k0 = 0; k0 < HID / 8; ++k0) {
        bf16x8 hv = *(const bf16x8*)(hr + k0 * 8);
        #pragma unroll
        for (int j = 0; j < 8; ++j) {
            float hk = (float)hv[j];
            #pragma unroll
            for (int c2 = 0; c2 < NCLS; ++c2) p[c2] += hk * wl[(k0 * 8 + j) * NCLS + c2];
        }
    }
    for (int c2 = 0; c2 < NCLS; ++c2) {
        red[tid] = p[c2];
        __syncthreads();
        for (int s = 128; s > 0; s >>= 1) {
            if (tid < s) red[tid] = fmaxf(red[tid], red[tid + s]);
            __syncthreads();
        }
        float mx = red[0];
        __syncthreads();
        red[tid] = __expf(p[c2] - mx);
        __syncthreads();
        for (int s = 128; s > 0; s >>= 1) {
            if (tid < s) red[tid] += red[tid + s];
            __syncthreads();
        }
        float lse = mx + __logf(red[0]);
        __syncthreads();
        out[tid * NCLS + c2] = p[c2] - lse;
    }
}

// ----------------------------------------------------------------------------
extern "C" void kernel_launch(void* const* d_in, const int* in_sizes, int n_in,
                              void* d_out, int out_size, void* d_ws, size_t ws_size,
                              hipStream_t stream) {
    const int*   x    = (const int*)d_in[0];
    const float* emb  = (const float*)d_in[1];
    const float* wgx  = (const float*)d_in[2];
    const float* wgh  = (const float*)d_in[3];
    const float* bg_  = (const float*)d_in[4];
    const float* wix  = (const float*)d_in[5];
    const float* wih  = (const float*)d_in[6];
    const float* bi_  = (const float*)d_in[7];
    const float* wfx  = (const float*)d_in[8];
    const float* wfh  = (const float*)d_in[9];
    const float* bf_  = (const float*)d_in[10];
    const float* wox  = (const float*)d_in[11];
    const float* woh  = (const float*)d_in[12];
    const float* bo_  = (const float*)d_in[13];
    const float* wph  = (const float*)d_in[14];
    const float* bp_  = (const float*)d_in[15];
    float* out = (float*)d_out;

    char* wsp = (char*)d_ws;
    int*            flags = (int*)wsp;                                      // 4 KB
    int*            xflag = (int*)(wsp + 4096);                             // 4 KB
    float*          XW    = (float*)(wsp + 8192);                           // 48 KB
    unsigned short* Wt    = (unsigned short*)(wsp + 8192 + 49152);          // 8 MB
    unsigned int*   hbuf32= (unsigned int*)(wsp + 8192 + 49152 + 8388608);  // 1 MB

    hipMemsetAsync(flags, 0, 8192, stream);                                  // flags+xflag
    hipMemsetAsync(hbuf32, 0, BATCH * HID * sizeof(unsigned short), stream); // h0 = 0

    prep_xw_kernel<<<48, 256, 0, stream>>>(emb, wgx, wix, wfx, wox,
                                           bg_, bi_, bf_, bo_, XW);
    prep_w_kernel<<<8192, 64, 0, stream>>>(wgh, wih, wfh, woh, Wt);

    void* args[] = { (void*)&x, (void*)&XW, (void*)&Wt, (void*)&hbuf32,
                     (void*)&flags, (void*)&xflag };
    hipError_t cerr = hipLaunchCooperativeKernel((void*)lstm_kernel, dim3(256), dim3(512),
                                                 args, 0, stream);
    if (cerr != hipSuccess) {
        // Fallback: plain launch. The flag protocol needs only co-residency,
        // which grid=256 at 1 WG/CU provides.
        lstm_kernel<<<dim3(256), dim3(512), 0, stream>>>(x, XW, Wt, hbuf32, flags, xflag);
    }

    proj_kernel<<<1, 256, 0, stream>>>((const unsigned short*)hbuf32, wph, bp_, out);
}

// Round 8
// 1711.154 us; speedup vs baseline: 3.1859x; 3.1859x over previous
//
#include <hip/hip_runtime.h>
#include <hip/hip_bf16.h>

#define T_SEQ 512
#define BATCH 256
#define HID   1024
#define EMBD  256
#define NCLS  10

typedef __bf16 bf16x8 __attribute__((ext_vector_type(8)));
typedef float  floatx16 __attribute__((ext_vector_type(16)));
typedef float  floatx2 __attribute__((ext_vector_type(2)));
typedef unsigned short ushortx8 __attribute__((ext_vector_type(8)));

__device__ __forceinline__ unsigned int f2bf(float f) {
    unsigned int u = __builtin_bit_cast(unsigned int, f);
    u += 0x7fffu + ((u >> 16) & 1u);
    return u >> 16;
}
__device__ __forceinline__ float sig_fast(float x) {
    return __builtin_amdgcn_rcpf(1.0f + __expf(-x));
}
__device__ __forceinline__ float tanh_fast(float x) {
    return 1.0f - 2.0f * __builtin_amdgcn_rcpf(1.0f + __expf(2.0f * x));
}

// -------------------- prep: XW[tok][gate][n] = emb[tok] @ Wx_gate + b_gate ---
__global__ void prep_xw_kernel(const float* __restrict__ emb,
                               const float* __restrict__ wgx, const float* __restrict__ wix,
                               const float* __restrict__ wfx, const float* __restrict__ wox,
                               const float* __restrict__ bg,  const float* __restrict__ bi,
                               const float* __restrict__ bf,  const float* __restrict__ bo,
                               float* __restrict__ XW) {
    int gid = blockIdx.x * blockDim.x + threadIdx.x;     // 3*4*1024 = 12288
    if (gid >= 3 * 4 * HID) return;
    int tok  = gid >> 12;
    int gate = (gid >> 10) & 3;
    int n    = gid & 1023;
    const float* W = gate == 0 ? wgx : gate == 1 ? wix : gate == 2 ? wfx : wox;
    const float* B = gate == 0 ? bg  : gate == 1 ? bi  : gate == 2 ? bf  : bo;
    float acc = B[n];
    const float* e = emb + tok * EMBD;
    for (int k = 0; k < EMBD; ++k) acc += e[k] * W[k * HID + n];
    XW[gid] = acc;
}

// ---- prep: Wt in 32x32x16 MFMA B-fragment order (R0 layout) ----
// frag = ((w*4+g)*2+kh)*32 + i ; Wt[frag*512 + lane*8 + e]
//   = bf16( W_g[k = kh*512 + i*16 + (lane>>5)*8 + e][j = w*32 + (lane&31)] )
__global__ void prep_w_kernel(const float* __restrict__ wgh, const float* __restrict__ wih,
                              const float* __restrict__ wfh, const float* __restrict__ woh,
                              unsigned short* __restrict__ Wt) {
    int bid = blockIdx.x;                 // 8192 = g(4) x kh(2) x i(32) x w(32)
    int w   = bid & 31;
    int i   = (bid >> 5) & 31;
    int kh  = (bid >> 10) & 1;
    int g   = bid >> 11;
    const float* W = g == 0 ? wgh : g == 1 ? wih : g == 2 ? wfh : woh;
    int lane = threadIdx.x;               // 64
    int j    = w * 32 + (lane & 31);
    int k0   = kh * 512 + i * 16 + (lane >> 5) * 8;
    ushortx8 o8;
    #pragma unroll
    for (int e = 0; e < 8; ++e) o8[e] = (unsigned short)f2bf(W[(k0 + e) * HID + j]);
    int frag = ((w * 4 + g) * 2 + kh) * 32 + i;
    *(ushortx8*)&Wt[frag * 512 + lane * 8] = o8;
}

// -------------------- persistent recurrent kernel ---------------------------
// 256 WGs x 512 threads. grp = blockIdx%8 owns 32 batch rows; w = blockIdx/8
// owns 32 hidden cols. Wave wv: gate gv = wv>>1, K-half kh = wv&1 (R0-proven
// structure: 8 partial tiles, 2-term GSUM).
//
// R14 = R0 + two surgical edits (everything else byte-identical):
//  (1) GEMM accumulator chain split 2x16: acc/acc2 interleaved, summed at
//      scatter. Halves the serial MFMA dependency chain (32 dependent MFMAs
//      ~1024 cyc/wave -> ~512) with zero change to LDS traffic/partials/ew.
//  (2) all-wave flag polling (read-only relaxed sc0 loads — R0's load class;
//      R10/R11 failures were fences/RMWs, not polls), removing the
//      spin->stage barrier: 4 -> 3 barriers/step. WAR on hs still ordered by
//      the scatter and ew barriers; depth-2 hbuf parity argument unchanged.
// R13 lesson (locked): A-path must stay global->LDS->fragments; per-lane
// direct loads are uncoalescable (64 lines per instruction, 3x regression).
__global__ __launch_bounds__(512, 2)
void lstm_kernel(const int* __restrict__ x, const float* __restrict__ XW,
                 const unsigned short* __restrict__ Wt,
                 unsigned int* __restrict__ hbuf32, int* __restrict__ flags,
                 int* __restrict__ xflag) {
    __shared__ unsigned short hs[32 * 1032];      // h stage, +8 shorts pad (66048 B)
    __shared__ float gbuf[8 * 32 * 36];           // [gate][kh][row][col+pad] (36864 B)
    __shared__ float xwl[384];                    // [tok][gate][32 cols]     (1536 B)
    __shared__ unsigned char xtok[32 * 512];      // tokens, byte-packed      (16384 B)
    __shared__ int use_local_sh;

    const int tid  = threadIdx.x;
    const int grp  = blockIdx.x & 7;
    const int w    = blockIdx.x >> 3;
    const int wv   = tid >> 6;
    const int gv   = wv >> 1;                  // gate
    const int kh   = wv & 1;                   // K-half
    const int lane = tid & 63;
    const int m32  = lane & 31;
    const int hv5  = lane >> 5;

    // ---- XCD-locality check (one-time, system-scope => placement-safe) ----
    {
        int xcc = 0;
        asm volatile("s_getreg_b32 %0, hwreg(HW_REG_XCC_ID)" : "=s"(xcc));
        if (tid == 0) {
            __hip_atomic_store(&xflag[grp * 32 + w], xcc + 1, __ATOMIC_RELAXED,
                               __HIP_MEMORY_SCOPE_SYSTEM);
        }
        if (wv == 0) {
            int v;
            for (;;) {
                v = __hip_atomic_load(&xflag[grp * 32 + (lane & 31)], __ATOMIC_RELAXED,
                                      __HIP_MEMORY_SCOPE_SYSTEM);
                if (__all(v != 0)) break;
                __builtin_amdgcn_s_sleep(2);
            }
            int v0 = __shfl(v, 0, 64);
            if (lane == 0) use_local_sh = __all(v == v0) ? 1 : 0;
        }
    }

    // one-time: B fragments into registers (128 regs/lane, AGPR-backed)
    bf16x8 Bf[32];
    {
        const unsigned short* wb = Wt + (size_t)(((w * 4 + gv) * 2 + kh) * 32) * 512
                                      + (size_t)lane * 8;
        #pragma unroll
        for (int i = 0; i < 32; ++i)
            Bf[i] = *(const bf16x8*)(wb + i * 512);
    }
    // one-time: XW slice into LDS
    if (tid < 384) {
        int tok = tid >> 7, g = (tid >> 5) & 3, jl = tid & 31;
        xwl[tid] = XW[(tok * 4 + g) * HID + w * 32 + jl];
    }
    // one-time: token table into LDS (byte-packed)
    #pragma unroll
    for (int it = 0; it < 32; ++it) {
        int flat = it * 512 + tid;                 // 16384 tokens
        int row  = flat >> 9;
        int col  = flat & 511;
        xtok[flat] = (unsigned char)x[(grp * 32 + row) * T_SEQ + col];
    }
    __syncthreads();
    const bool use_local = (use_local_sh != 0);

    // elementwise ownership: thread -> row = tid>>4, cols jc2*2..+2
    const int erow = tid >> 4;
    const int jc2  = tid & 15;
    float cst[2] = {0.f, 0.f};
    unsigned long long* hs64 = (unsigned long long*)hs;

    for (int s = 0; s < T_SEQ; ++s) {
        // ---- wait for h(s): EVERY wave polls all 32 flags (no barrier) ----
        if (s > 0) {
            const int fidx = grp * 32 + (lane & 31);
            if (use_local) {
                for (;;) {
                    int v = __hip_atomic_load(&flags[fidx], __ATOMIC_RELAXED,
                                              __HIP_MEMORY_SCOPE_AGENT);
                    if (__all(v >= s)) break;
                    __builtin_amdgcn_s_sleep(1);
                }
            } else {
                for (;;) {
                    int v = __hip_atomic_load(&flags[fidx], __ATOMIC_RELAXED,
                                              __HIP_MEMORY_SCOPE_SYSTEM);
                    if (__all(v >= s)) break;
                    __builtin_amdgcn_s_sleep(1);
                }
            }
            asm volatile("" ::: "memory");     // compiler barrier only
        }

        // ---- stage h(s)[32 rows x 256 qwords] into padded LDS ----
        const unsigned long long* hp64 = (const unsigned long long*)
            (hbuf32 + (size_t)(s & 1) * (BATCH * HID / 2)) + (size_t)grp * 32 * 256;
        {
            unsigned long long tmp[16];
            if (use_local) {
                #pragma unroll
                for (int it = 0; it < 16; ++it) {
                    int flat = it * 512 + tid;         // 8192 qwords
                    tmp[it] = __hip_atomic_load(&hp64[(flat >> 8) * 256 + (flat & 255)],
                                                __ATOMIC_RELAXED, __HIP_MEMORY_SCOPE_AGENT);
                }
            } else {
                #pragma unroll
                for (int it = 0; it < 16; ++it) {
                    int flat = it * 512 + tid;
                    tmp[it] = __hip_atomic_load(&hp64[(flat >> 8) * 256 + (flat & 255)],
                                                __ATOMIC_RELAXED, __HIP_MEMORY_SCOPE_SYSTEM);
                }
            }
            #pragma unroll
            for (int it = 0; it < 16; ++it) {
                int flat = it * 512 + tid;
                hs64[(flat >> 8) * 258 + (flat & 255)] = tmp[it];
            }
        }
        __syncthreads();                       // barrier b: hs staged

        // ---- GEMM: 32x32 tile, split 2x16 acc chains, B from registers ----
        floatx16 acc  = {0.f,0.f,0.f,0.f,0.f,0.f,0.f,0.f,0.f,0.f,0.f,0.f,0.f,0.f,0.f,0.f};
        floatx16 acc2 = {0.f,0.f,0.f,0.f,0.f,0.f,0.f,0.f,0.f,0.f,0.f,0.f,0.f,0.f,0.f,0.f};
        const unsigned short* ap = hs + m32 * 1032 + kh * 512 + hv5 * 8;
        #pragma unroll
        for (int i = 0; i < 16; ++i) {
            bf16x8 a0 = *(const bf16x8*)(ap + i * 16);
            bf16x8 a1 = *(const bf16x8*)(ap + (i + 16) * 16);
            acc  = __builtin_amdgcn_mfma_f32_32x32x16_bf16(a0, Bf[i],      acc,  0, 0, 0);
            acc2 = __builtin_amdgcn_mfma_f32_32x32x16_bf16(a1, Bf[i + 16], acc2, 0, 0, 0);
        }

        // ---- scatter C (col=lane&31, row=(reg&3)+8*(reg>>2)+4*(lane>>5)) ----
        {
            float* gb = &gbuf[(size_t)(gv * 2 + kh) * 32 * 36];
            #pragma unroll
            for (int reg = 0; reg < 16; ++reg) {
                int row = (reg & 3) + 8 * (reg >> 2) + 4 * hv5;
                gb[row * 36 + m32] = acc[reg] + acc2[reg];
            }
        }
        __syncthreads();                       // barrier c: gbuf complete

        // ---- elementwise LSTM cell update, h(s+1) out ----
        {
            int tk = xtok[erow * 512 + s];
            const float* xb = &xwl[tk * 128];
            const int go = erow * 36 + jc2 * 2;
            floatx2 ag = *(const floatx2*)&gbuf[0 * 32 * 36 + go]
                       + *(const floatx2*)&gbuf[1 * 32 * 36 + go];
            floatx2 ai = *(const floatx2*)&gbuf[2 * 32 * 36 + go]
                       + *(const floatx2*)&gbuf[3 * 32 * 36 + go];
            floatx2 af = *(const floatx2*)&gbuf[4 * 32 * 36 + go]
                       + *(const floatx2*)&gbuf[5 * 32 * 36 + go];
            floatx2 ao = *(const floatx2*)&gbuf[6 * 32 * 36 + go]
                       + *(const floatx2*)&gbuf[7 * 32 * 36 + go];
            floatx2 xg = *(const floatx2*)&xb[0 * 32 + jc2 * 2];
            floatx2 xi = *(const floatx2*)&xb[1 * 32 + jc2 * 2];
            floatx2 xf = *(const floatx2*)&xb[2 * 32 + jc2 * 2];
            floatx2 xo = *(const floatx2*)&xb[3 * 32 + jc2 * 2];
            unsigned int hvv[2];
            #pragma unroll
            for (int u = 0; u < 2; ++u) {
                float g  = tanh_fast(ag[u] + xg[u]);
                float ii = sig_fast(ai[u] + xi[u]);
                float ff = sig_fast(af[u] + xf[u]);
                float oo = sig_fast(ao[u] + xo[u]);
                float cn = g * ii + cst[u] * ff;
                float h  = tanh_fast(cn) * oo;
                cst[u]   = (tk != 0) ? cn : 0.0f;   // pad = ((x+1)//2) in {0,1,1}
                hvv[u]   = f2bf(h);
            }
            unsigned int* hnext = hbuf32 + (size_t)((s + 1) & 1) * (BATCH * HID / 2);
            unsigned int* hp = &hnext[((grp * 32 + erow) * HID + w * 32 + jc2 * 2) >> 1];
            unsigned int hval = hvv[0] | (hvv[1] << 16);
            if (use_local) {
                // plain write-back store into the shared XCD L2 (no LLC RTT)
                __hip_atomic_store(hp, hval, __ATOMIC_RELAXED, __HIP_MEMORY_SCOPE_WORKGROUP);
            } else {
                __hip_atomic_store(hp, hval, __ATOMIC_RELAXED, __HIP_MEMORY_SCOPE_SYSTEM);
            }
        }
        // syncthreads drains each wave's vmcnt before s_barrier => on exit, all
        // h stores of this WG are complete at their coherence point (L2 local /
        // LLC fallback) before the flag is published.
        __syncthreads();                       // barrier d

        if (s < T_SEQ - 1 && tid == 0) {
            if (use_local) {
                __hip_atomic_store(&flags[grp * 32 + w], s + 1,
                                   __ATOMIC_RELAXED, __HIP_MEMORY_SCOPE_WORKGROUP);
            } else {
                __hip_atomic_store(&flags[grp * 32 + w], s + 1,
                                   __ATOMIC_RELAXED, __HIP_MEMORY_SCOPE_SYSTEM);
            }
        }
    }
}

// -------------------- projection + log_softmax over batch dim ---------------
__global__ void proj_kernel(const unsigned short* __restrict__ h,
                            const float* __restrict__ wph, const float* __restrict__ bp,
                            float* __restrict__ out) {
    __shared__ float wl[HID * NCLS];
    __shared__ float red[256];
    int tid = threadIdx.x;      // = batch row
    for (int i = tid; i < HID * NCLS; i += 256) wl[i] = wph[i];
    __syncthreads();
    float p[NCLS];
    #pragma unroll
    for (int c2 = 0; c2 < NCLS; ++c2) p[c2] = bp[c2];
    const unsigned short* hr = h + tid * HID;
    for (int k0 = 0; k0 < HID / 8; ++k0) {
        bf16x8 hv = *(const bf16x8*)(hr + k0 * 8);
        #pragma unroll
        for (int j = 0; j < 8; ++j) {
            float hk = (float)hv[j];
            #pragma unroll
            for (int c2 = 0; c2 < NCLS; ++c2) p[c2] += hk * wl[(k0 * 8 + j) * NCLS + c2];
        }
    }
    for (int c2 = 0; c2 < NCLS; ++c2) {
        red[tid] = p[c2];
        __syncthreads();
        for (int s = 128; s > 0; s >>= 1) {
            if (tid < s) red[tid] = fmaxf(red[tid], red[tid + s]);
            __syncthreads();
        }
        float mx = red[0];
        __syncthreads();
        red[tid] = __expf(p[c2] - mx);
        __syncthreads();
        for (int s = 128; s > 0; s >>= 1) {
            if (tid < s) red[tid] += red[tid + s];
            __syncthreads();
        }
        float lse = mx + __logf(red[0]);
        __syncthreads();
        out[tid * NCLS + c2] = p[c2] - lse;
    }
}

// ----------------------------------------------------------------------------
extern "C" void kernel_launch(void* const* d_in, const int* in_sizes, int n_in,
                              void* d_out, int out_size, void* d_ws, size_t ws_size,
                              hipStream_t stream) {
    const int*   x    = (const int*)d_in[0];
    const float* emb  = (const float*)d_in[1];
    const float* wgx  = (const float*)d_in[2];
    const float* wgh  = (const float*)d_in[3];
    const float* bg_  = (const float*)d_in[4];
    const float* wix  = (const float*)d_in[5];
    const float* wih  = (const float*)d_in[6];
    const float* bi_  = (const float*)d_in[7];
    const float* wfx  = (const float*)d_in[8];
    const float* wfh  = (const float*)d_in[9];
    const float* bf_  = (const float*)d_in[10];
    const float* wox  = (const float*)d_in[11];
    const float* woh  = (const float*)d_in[12];
    const float* bo_  = (const float*)d_in[13];
    const float* wph  = (const float*)d_in[14];
    const float* bp_  = (const float*)d_in[15];
    float* out = (float*)d_out;

    char* wsp = (char*)d_ws;
    int*            flags = (int*)wsp;                                      // 4 KB
    int*            xflag = (int*)(wsp + 4096);                             // 4 KB
    float*          XW    = (float*)(wsp + 8192);                           // 48 KB
    unsigned short* Wt    = (unsigned short*)(wsp + 8192 + 49152);          // 8 MB
    unsigned int*   hbuf32= (unsigned int*)(wsp + 8192 + 49152 + 8388608);  // 1 MB

    hipMemsetAsync(flags, 0, 8192, stream);                                  // flags+xflag
    hipMemsetAsync(hbuf32, 0, BATCH * HID * sizeof(unsigned short), stream); // h0 = 0

    prep_xw_kernel<<<48, 256, 0, stream>>>(emb, wgx, wix, wfx, wox,
                                           bg_, bi_, bf_, bo_, XW);
    prep_w_kernel<<<8192, 64, 0, stream>>>(wgh, wih, wfh, woh, Wt);

    void* args[] = { (void*)&x, (void*)&XW, (void*)&Wt, (void*)&hbuf32,
                     (void*)&flags, (void*)&xflag };
    hipError_t cerr = hipLaunchCooperativeKernel((void*)lstm_kernel, dim3(256), dim3(512),
                                                 args, 0, stream);
    if (cerr != hipSuccess) {
        // Fallback: plain launch. The flag protocol needs only co-residency,
        // which grid=256 at 1 WG/CU provides.
        lstm_kernel<<<dim3(256), dim3(512), 0, stream>>>(x, XW, Wt, hbuf32, flags, xflag);
    }

    proj_kernel<<<1, 256, 0, stream>>>((const unsigned short*)hbuf32, wph, bp_, out);
}

// Round 10
// 1531.386 us; speedup vs baseline: 3.5598x; 1.1174x over previous
//
#include <hip/hip_runtime.h>
#include <hip/hip_bf16.h>

#define T_SEQ 512
#define BATCH 256
#define HID   1024
#define EMBD  256
#define NCLS  10

typedef __bf16 bf16x8 __attribute__((ext_vector_type(8)));
typedef float  floatx16 __attribute__((ext_vector_type(16)));
typedef float  floatx2 __attribute__((ext_vector_type(2)));
typedef unsigned short ushortx8 __attribute__((ext_vector_type(8)));

__device__ __forceinline__ unsigned int f2bf(float f) {
    unsigned int u = __builtin_bit_cast(unsigned int, f);
    u += 0x7fffu + ((u >> 16) & 1u);
    return u >> 16;
}
__device__ __forceinline__ float sig_fast(float x) {
    return __builtin_amdgcn_rcpf(1.0f + __expf(-x));
}
__device__ __forceinline__ float tanh_fast(float x) {
    return 1.0f - 2.0f * __builtin_amdgcn_rcpf(1.0f + __expf(2.0f * x));
}

// -------------------- prep: XW[tok][gate][n] = emb[tok] @ Wx_gate + b_gate ---
__global__ void prep_xw_kernel(const float* __restrict__ emb,
                               const float* __restrict__ wgx, const float* __restrict__ wix,
                               const float* __restrict__ wfx, const float* __restrict__ wox,
                               const float* __restrict__ bg,  const float* __restrict__ bi,
                               const float* __restrict__ bf,  const float* __restrict__ bo,
                               float* __restrict__ XW) {
    int gid = blockIdx.x * blockDim.x + threadIdx.x;     // 3*4*1024 = 12288
    if (gid >= 3 * 4 * HID) return;
    int tok  = gid >> 12;
    int gate = (gid >> 10) & 3;
    int n    = gid & 1023;
    const float* W = gate == 0 ? wgx : gate == 1 ? wix : gate == 2 ? wfx : wox;
    const float* B = gate == 0 ? bg  : gate == 1 ? bi  : gate == 2 ? bf  : bo;
    float acc = B[n];
    const float* e = emb + tok * EMBD;
    for (int k = 0; k < EMBD; ++k) acc += e[k] * W[k * HID + n];
    XW[gid] = acc;
}

// ---- prep: Wt in 32x32x16 MFMA B-fragment order (R0 layout) ----
// frag = ((w*4+g)*2+kh)*32 + i ; Wt[frag*512 + lane*8 + e]
//   = bf16( W_g[k = kh*512 + i*16 + (lane>>5)*8 + e][j = w*32 + (lane&31)] )
__global__ void prep_w_kernel(const float* __restrict__ wgh, const float* __restrict__ wih,
                              const float* __restrict__ wfh, const float* __restrict__ woh,
                              unsigned short* __restrict__ Wt) {
    int bid = blockIdx.x;                 // 8192 = g(4) x kh(2) x i(32) x w(32)
    int w   = bid & 31;
    int i   = (bid >> 5) & 31;
    int kh  = (bid >> 10) & 1;
    int g   = bid >> 11;
    const float* W = g == 0 ? wgh : g == 1 ? wih : g == 2 ? wfh : woh;
    int lane = threadIdx.x;               // 64
    int j    = w * 32 + (lane & 31);
    int k0   = kh * 512 + i * 16 + (lane >> 5) * 8;
    ushortx8 o8;
    #pragma unroll
    for (int e = 0; e < 8; ++e) o8[e] = (unsigned short)f2bf(W[(k0 + e) * HID + j]);
    int frag = ((w * 4 + g) * 2 + kh) * 32 + i;
    *(ushortx8*)&Wt[frag * 512 + lane * 8] = o8;
}

// -------------------- persistent recurrent kernel ---------------------------
// 256 WGs x 512 threads. grp = blockIdx%8 owns 32 batch rows; w = blockIdx/8
// owns 32 hidden cols. Wave wv: gate gv = wv>>1, K-half kh = wv&1 (R0-proven
// structure: 8 partial tiles, 2-term GSUM).
//
// R15 (resubmitted after infra failure) = R14 + ONE change: local-path
// staging via global_load_lds (width 16, aux=1 => sc0/L1-bypass, same
// coherence class as the agent-scope loads it replaces). Deletes the VGPR
// round trip (16 loads -> tmp[16] -> 16 ds_writes + ~20 VALU addr per
// thread); each wave DMAs its 4 rows as 8 x 1KB ops (per-lane global src,
// wave-uniform LDS dest; each op sits fully inside one padded 2064B row).
// Completion covered by barrier b's vmcnt(0). Fallback staging unchanged.
// R14 edits retained: 2x16 split MFMA chains; all-wave flag polling
// (3 barriers/step). R13 lesson: A-path must stay global->LDS->fragments.
__global__ __launch_bounds__(512, 2)
void lstm_kernel(const int* __restrict__ x, const float* __restrict__ XW,
                 const unsigned short* __restrict__ Wt,
                 unsigned int* __restrict__ hbuf32, int* __restrict__ flags,
                 int* __restrict__ xflag) {
    __shared__ unsigned short hs[32 * 1032];      // h stage, +8 shorts pad (66048 B)
    __shared__ float gbuf[8 * 32 * 36];           // [gate][kh][row][col+pad] (36864 B)
    __shared__ float xwl[384];                    // [tok][gate][32 cols]     (1536 B)
    __shared__ unsigned char xtok[32 * 512];      // tokens, byte-packed      (16384 B)
    __shared__ int use_local_sh;

    const int tid  = threadIdx.x;
    const int grp  = blockIdx.x & 7;
    const int w    = blockIdx.x >> 3;
    const int wv   = tid >> 6;
    const int gv   = wv >> 1;                  // gate
    const int kh   = wv & 1;                   // K-half
    const int lane = tid & 63;
    const int m32  = lane & 31;
    const int hv5  = lane >> 5;

    // ---- XCD-locality check (one-time, system-scope => placement-safe) ----
    {
        int xcc = 0;
        asm volatile("s_getreg_b32 %0, hwreg(HW_REG_XCC_ID)" : "=s"(xcc));
        if (tid == 0) {
            __hip_atomic_store(&xflag[grp * 32 + w], xcc + 1, __ATOMIC_RELAXED,
                               __HIP_MEMORY_SCOPE_SYSTEM);
        }
        if (wv == 0) {
            int v;
            for (;;) {
                v = __hip_atomic_load(&xflag[grp * 32 + (lane & 31)], __ATOMIC_RELAXED,
                                      __HIP_MEMORY_SCOPE_SYSTEM);
                if (__all(v != 0)) break;
                __builtin_amdgcn_s_sleep(2);
            }
            int v0 = __shfl(v, 0, 64);
            if (lane == 0) use_local_sh = __all(v == v0) ? 1 : 0;
        }
    }

    // one-time: B fragments into registers (128 regs/lane, AGPR-backed)
    bf16x8 Bf[32];
    {
        const unsigned short* wb = Wt + (size_t)(((w * 4 + gv) * 2 + kh) * 32) * 512
                                      + (size_t)lane * 8;
        #pragma unroll
        for (int i = 0; i < 32; ++i)
            Bf[i] = *(const bf16x8*)(wb + i * 512);
    }
    // one-time: XW slice into LDS
    if (tid < 384) {
        int tok = tid >> 7, g = (tid >> 5) & 3, jl = tid & 31;
        xwl[tid] = XW[(tok * 4 + g) * HID + w * 32 + jl];
    }
    // one-time: token table into LDS (byte-packed)
    #pragma unroll
    for (int it = 0; it < 32; ++it) {
        int flat = it * 512 + tid;                 // 16384 tokens
        int row  = flat >> 9;
        int col  = flat & 511;
        xtok[flat] = (unsigned char)x[(grp * 32 + row) * T_SEQ + col];
    }
    __syncthreads();
    const bool use_local = (use_local_sh != 0);

    // elementwise ownership: thread -> row = tid>>4, cols jc2*2..+2
    const int erow = tid >> 4;
    const int jc2  = tid & 15;
    float cst[2] = {0.f, 0.f};
    unsigned long long* hs64 = (unsigned long long*)hs;

    for (int s = 0; s < T_SEQ; ++s) {
        // ---- wait for h(s): EVERY wave polls all 32 flags (no barrier) ----
        if (s > 0) {
            const int fidx = grp * 32 + (lane & 31);
            if (use_local) {
                for (;;) {
                    int v = __hip_atomic_load(&flags[fidx], __ATOMIC_RELAXED,
                                              __HIP_MEMORY_SCOPE_AGENT);
                    if (__all(v >= s)) break;
                    __builtin_amdgcn_s_sleep(1);
                }
            } else {
                for (;;) {
                    int v = __hip_atomic_load(&flags[fidx], __ATOMIC_RELAXED,
                                              __HIP_MEMORY_SCOPE_SYSTEM);
                    if (__all(v >= s)) break;
                    __builtin_amdgcn_s_sleep(1);
                }
            }
            asm volatile("" ::: "memory");     // compiler barrier only
        }

        // ---- stage h(s)[32 rows x 2048 B] into padded LDS ----
        const unsigned long long* hp64 = (const unsigned long long*)
            (hbuf32 + (size_t)(s & 1) * (BATCH * HID / 2)) + (size_t)grp * 32 * 256;
        if (use_local) {
            // wave wv DMAs rows wv*4..+4 via global_load_lds: 2 x 1KB per row
            // (per-lane global src = rowbase + lane*16; wave-uniform LDS dest;
            //  aux=1 -> sc0, bypass stale L1; vmcnt drained by barrier b).
            const char* gbase = (const char*)hp64;
            #pragma unroll
            for (int r = 0; r < 4; ++r) {
                int row = wv * 4 + r;
                const char* src0 = gbase + row * 2048 + lane * 16;
                __builtin_amdgcn_global_load_lds(
                    (const __attribute__((address_space(1))) unsigned int*)src0,
                    (__attribute__((address_space(3))) unsigned int*)&hs[row * 1032],
                    16, 0, 1);
                __builtin_amdgcn_global_load_lds(
                    (const __attribute__((address_space(1))) unsigned int*)(src0 + 1024),
                    (__attribute__((address_space(3))) unsigned int*)&hs[row * 1032 + 512],
                    16, 0, 1);
            }
        } else {
            unsigned long long tmp[16];
            #pragma unroll
            for (int it = 0; it < 16; ++it) {
                int flat = it * 512 + tid;         // 8192 qwords
                tmp[it] = __hip_atomic_load(&hp64[(flat >> 8) * 256 + (flat & 255)],
                                            __ATOMIC_RELAXED, __HIP_MEMORY_SCOPE_SYSTEM);
            }
            #pragma unroll
            for (int it = 0; it < 16; ++it) {
                int flat = it * 512 + tid;
                hs64[(flat >> 8) * 258 + (flat & 255)] = tmp[it];
            }
        }
        __syncthreads();                       // barrier b: hs staged (vmcnt+lgkm drain)

        // ---- GEMM: 32x32 tile, split 2x16 acc chains, B from registers ----
        floatx16 acc  = {0.f,0.f,0.f,0.f,0.f,0.f,0.f,0.f,0.f,0.f,0.f,0.f,0.f,0.f,0.f,0.f};
        floatx16 acc2 = {0.f,0.f,0.f,0.f,0.f,0.f,0.f,0.f,0.f,0.f,0.f,0.f,0.f,0.f,0.f,0.f};
        const unsigned short* ap = hs + m32 * 1032 + kh * 512 + hv5 * 8;
        #pragma unroll
        for (int i = 0; i < 16; ++i) {
            bf16x8 a0 = *(const bf16x8*)(ap + i * 16);
            bf16x8 a1 = *(const bf16x8*)(ap + (i + 16) * 16);
            acc  = __builtin_amdgcn_mfma_f32_32x32x16_bf16(a0, Bf[i],      acc,  0, 0, 0);
            acc2 = __builtin_amdgcn_mfma_f32_32x32x16_bf16(a1, Bf[i + 16], acc2, 0, 0, 0);
        }

        // ---- scatter C (col=lane&31, row=(reg&3)+8*(reg>>2)+4*(lane>>5)) ----
        {
            float* gb = &gbuf[(size_t)(gv * 2 + kh) * 32 * 36];
            #pragma unroll
            for (int reg = 0; reg < 16; ++reg) {
                int row = (reg & 3) + 8 * (reg >> 2) + 4 * hv5;
                gb[row * 36 + m32] = acc[reg] + acc2[reg];
            }
        }
        __syncthreads();                       // barrier c: gbuf complete

        // ---- elementwise LSTM cell update, h(s+1) out ----
        {
            int tk = xtok[erow * 512 + s];
            const float* xb = &xwl[tk * 128];
            const int go = erow * 36 + jc2 * 2;
            floatx2 ag = *(const floatx2*)&gbuf[0 * 32 * 36 + go]
                       + *(const floatx2*)&gbuf[1 * 32 * 36 + go];
            floatx2 ai = *(const floatx2*)&gbuf[2 * 32 * 36 + go]
                       + *(const floatx2*)&gbuf[3 * 32 * 36 + go];
            floatx2 af = *(const floatx2*)&gbuf[4 * 32 * 36 + go]
                       + *(const floatx2*)&gbuf[5 * 32 * 36 + go];
            floatx2 ao = *(const floatx2*)&gbuf[6 * 32 * 36 + go]
                       + *(const floatx2*)&gbuf[7 * 32 * 36 + go];
            floatx2 xg = *(const floatx2*)&xb[0 * 32 + jc2 * 2];
            floatx2 xi = *(const floatx2*)&xb[1 * 32 + jc2 * 2];
            floatx2 xf = *(const floatx2*)&xb[2 * 32 + jc2 * 2];
            floatx2 xo = *(const floatx2*)&xb[3 * 32 + jc2 * 2];
            unsigned int hvv[2];
            #pragma unroll
            for (int u = 0; u < 2; ++u) {
                float g  = tanh_fast(ag[u] + xg[u]);
                float ii = sig_fast(ai[u] + xi[u]);
                float ff = sig_fast(af[u] + xf[u]);
                float oo = sig_fast(ao[u] + xo[u]);
                float cn = g * ii + cst[u] * ff;
                float h  = tanh_fast(cn) * oo;
                cst[u]   = (tk != 0) ? cn : 0.0f;   // pad = ((x+1)//2) in {0,1,1}
                hvv[u]   = f2bf(h);
            }
            unsigned int* hnext = hbuf32 + (size_t)((s + 1) & 1) * (BATCH * HID / 2);
            unsigned int* hp = &hnext[((grp * 32 + erow) * HID + w * 32 + jc2 * 2) >> 1];
            unsigned int hval = hvv[0] | (hvv[1] << 16);
            if (use_local) {
                // plain write-back store into the shared XCD L2 (no LLC RTT)
                __hip_atomic_store(hp, hval, __ATOMIC_RELAXED, __HIP_MEMORY_SCOPE_WORKGROUP);
            } else {
                __hip_atomic_store(hp, hval, __ATOMIC_RELAXED, __HIP_MEMORY_SCOPE_SYSTEM);
            }
        }
        // syncthreads drains each wave's vmcnt before s_barrier => on exit, all
        // h stores of this WG are complete at their coherence point (L2 local /
        // LLC fallback) before the flag is published.
        __syncthreads();                       // barrier d

        if (s < T_SEQ - 1 && tid == 0) {
            if (use_local) {
                __hip_atomic_store(&flags[grp * 32 + w], s + 1,
                                   __ATOMIC_RELAXED, __HIP_MEMORY_SCOPE_WORKGROUP);
            } else {
                __hip_atomic_store(&flags[grp * 32 + w], s + 1,
                                   __ATOMIC_RELAXED, __HIP_MEMORY_SCOPE_SYSTEM);
            }
        }
    }
}

// -------------------- projection + log_softmax over batch dim ---------------
__global__ void proj_kernel(const unsigned short* __restrict__ h,
                            const float* __restrict__ wph, const float* __restrict__ bp,
                            float* __restrict__ out) {
    __shared__ float wl[HID * NCLS];
    __shared__ float red[256];
    int tid = threadIdx.x;      // = batch row
    for (int i = tid; i < HID * NCLS; i += 256) wl[i] = wph[i];
    __syncthreads();
    float p[NCLS];
    #pragma unroll
    for (int c2 = 0; c2 < NCLS; ++c2) p[c2] = bp[c2];
    const unsigned short* hr = h + tid * HID;
    for (int k0 = 0; k0 < HID / 8; ++k0) {
        bf16x8 hv = *(const bf16x8*)(hr + k0 * 8);
        #pragma unroll
        for (int j = 0; j < 8; ++j) {
            float hk = (float)hv[j];
            #pragma unroll
            for (int c2 = 0; c2 < NCLS; ++c2) p[c2] += hk * wl[(k0 * 8 + j) * NCLS + c2];
        }
    }
    for (int c2 = 0; c2 < NCLS; ++c2) {
        red[tid] = p[c2];
        __syncthreads();
        for (int s = 128; s > 0; s >>= 1) {
            if (tid < s) red[tid] = fmaxf(red[tid], red[tid + s]);
            __syncthreads();
        }
        float mx = red[0];
        __syncthreads();
        red[tid] = __expf(p[c2] - mx);
        __syncthreads();
        for (int s = 128; s > 0; s >>= 1) {
            if (tid < s) red[tid] += red[tid + s];
            __syncthreads();
        }
        float lse = mx + __logf(red[0]);
        __syncthreads();
        out[tid * NCLS + c2] = p[c2] - lse;
    }
}

// ----------------------------------------------------------------------------
extern "C" void kernel_launch(void* const* d_in, const int* in_sizes, int n_in,
                              void* d_out, int out_size, void* d_ws, size_t ws_size,
                              hipStream_t stream) {
    const int*   x    = (const int*)d_in[0];
    const float* emb  = (const float*)d_in[1];
    const float* wgx  = (const float*)d_in[2];
    const float* wgh  = (const float*)d_in[3];
    const float* bg_  = (const float*)d_in[4];
    const float* wix  = (const float*)d_in[5];
    const float* wih  = (const float*)d_in[6];
    const float* bi_  = (const float*)d_in[7];
    const float* wfx  = (const float*)d_in[8];
    const float* wfh  = (const float*)d_in[9];
    const float* bf_  = (const float*)d_in[10];
    const float* wox  = (const float*)d_in[11];
    const float* woh  = (const float*)d_in[12];
    const float* bo_  = (const float*)d_in[13];
    const float* wph  = (const float*)d_in[14];
    const float* bp_  = (const float*)d_in[15];
    float* out = (float*)d_out;

    char* wsp = (char*)d_ws;
    int*            flags = (int*)wsp;                                      // 4 KB
    int*            xflag = (int*)(wsp + 4096);                             // 4 KB
    float*          XW    = (float*)(wsp + 8192);                           // 48 KB
    unsigned short* Wt    = (unsigned short*)(wsp + 8192 + 49152);          // 8 MB
    unsigned int*   hbuf32= (unsigned int*)(wsp + 8192 + 49152 + 8388608);  // 1 MB

    hipMemsetAsync(flags, 0, 8192, stream);                                  // flags+xflag
    hipMemsetAsync(hbuf32, 0, BATCH * HID * sizeof(unsigned short), stream); // h0 = 0

    prep_xw_kernel<<<48, 256, 0, stream>>>(emb, wgx, wix, wfx, wox,
                                           bg_, bi_, bf_, bo_, XW);
    prep_w_kernel<<<8192, 64, 0, stream>>>(wgh, wih, wfh, woh, Wt);

    void* args[] = { (void*)&x, (void*)&XW, (void*)&Wt, (void*)&hbuf32,
                     (void*)&flags, (void*)&xflag };
    hipError_t cerr = hipLaunchCooperativeKernel((void*)lstm_kernel, dim3(256), dim3(512),
                                                 args, 0, stream);
    if (cerr != hipSuccess) {
        // Fallback: plain launch. The flag protocol needs only co-residency,
        // which grid=256 at 1 WG/CU provides.
        lstm_kernel<<<dim3(256), dim3(512), 0, stream>>>(x, XW, Wt, hbuf32, flags, xflag);
    }

    proj_kernel<<<1, 256, 0, stream>>>((const unsigned short*)hbuf32, wph, bp_, out);
}